// Round 2
// baseline (1061.396 us; speedup 1.0000x reference)
//
#include <hip/hip_runtime.h>

#define U_DIM 2000
#define V_DIM 2000
#define F_DIM 2000
#define R_DIM 5
#define H_DIM 64
#define O_DIM 75
#define SH_DIM 64
#define SF_DIM 128
#define CAT_DIM (2 * R_DIM * H_DIM + SH_DIM) /* 704 */

struct GemmArgs {
  const float* A0; const float* B0; const float* bias0; float* C0;
  const float* A1; const float* B1; const float* bias1; float* C1;
  long sA, sB, sC;
  int zSplit;
  int M, N, K;
};

// C = A[M,K] @ B[K,N] (+bias) (+relu), row-major, batched over z with two
// pointer-sets (z < zSplit -> set 0). BM = 16*TM, BN = 64, BK = 16.
template<int TM, bool RELU, bool BIAS>
__launch_bounds__(256)
__global__ void gemm_nn(GemmArgs g) {
  constexpr int BM = 16 * TM;
  constexpr int BN = 64;
  constexpr int BK = 16;
  const int z = blockIdx.z;
  const float *A, *B, *bias;
  float* C;
  int zi;
  if (z < g.zSplit) { zi = z;            A = g.A0; B = g.B0; bias = g.bias0; C = g.C0; }
  else              { zi = z - g.zSplit; A = g.A1; B = g.B1; bias = g.bias1; C = g.C1; }
  A += (long)zi * g.sA;
  B += (long)zi * g.sB;
  C += (long)zi * g.sC;
  const int M = g.M, N = g.N, K = g.K;
  const int row0 = blockIdx.x * BM;
  const int col0 = blockIdx.y * BN;

  __shared__ float As[BK][BM + 4];  // transposed A tile: As[k][m], row 16B-aligned
  __shared__ float Bs[BK][BN];

  const int tid = threadIdx.x;
  const int tx = tid & 15;
  const int ty = tid >> 4;

  float acc[TM][4];
#pragma unroll
  for (int i = 0; i < TM; ++i)
#pragma unroll
    for (int j = 0; j < 4; ++j) acc[i][j] = 0.f;

  for (int k0 = 0; k0 < K; k0 += BK) {
    // A tile: BM x BK, consecutive tid -> consecutive k (64B segments per row)
#pragma unroll
    for (int idx = tid; idx < BM * BK; idx += 256) {
      int r = idx >> 4;
      int k = idx & 15;
      int gr = row0 + r, gk = k0 + k;
      float v = 0.f;
      if (gr < M && gk < K) v = A[(long)gr * K + gk];
      As[k][r] = v;
    }
    // B tile: BK x BN, consecutive tid -> consecutive n (fully coalesced)
#pragma unroll
    for (int idx = tid; idx < BK * BN; idx += 256) {
      int k = idx >> 6;
      int n = idx & 63;
      int gk = k0 + k, gn = col0 + n;
      Bs[k][n] = (gk < K && gn < N) ? B[(long)gk * N + gn] : 0.f;
    }
    __syncthreads();
#pragma unroll
    for (int k = 0; k < BK; ++k) {
      float av[TM], bv[4];
#pragma unroll
      for (int i = 0; i < TM; ++i) av[i] = As[k][ty * TM + i];
#pragma unroll
      for (int j = 0; j < 4; ++j) bv[j] = Bs[k][tx * 4 + j];
#pragma unroll
      for (int i = 0; i < TM; ++i)
#pragma unroll
        for (int j = 0; j < 4; ++j) acc[i][j] = fmaf(av[i], bv[j], acc[i][j]);
    }
    __syncthreads();
  }

#pragma unroll
  for (int i = 0; i < TM; ++i) {
    int r = row0 + ty * TM + i;
    if (r >= M) continue;
#pragma unroll
    for (int j = 0; j < 4; ++j) {
      int c = col0 + tx * 4 + j;
      if (c >= N) continue;
      float v = acc[i][j];
      if (BIAS) v += bias[c];
      if (RELU) v = fmaxf(v, 0.f);
      C[(long)r * N + c] = v;
    }
  }
}

// Column mean / rstd for two [rows, C] tensors (biased variance, matches BN train).
// mv layout: mv[0..C) = mean, mv[C..2C) = rsqrt(var + eps). grid = (C, 2), 256 thr.
__global__ void colstats2(const float* __restrict__ X0, const float* __restrict__ X1,
                          int rows, int C, float* mv0, float* mv1, float eps) {
  const float* X = blockIdx.y ? X1 : X0;
  float* mv = blockIdx.y ? mv1 : mv0;
  const int c = blockIdx.x;
  float s = 0.f, sq = 0.f;
  for (int r = threadIdx.x; r < rows; r += 256) {
    float x = X[(long)r * C + c];
    s += x;
    sq += x * x;
  }
#pragma unroll
  for (int off = 32; off > 0; off >>= 1) {
    s += __shfl_down(s, off, 64);
    sq += __shfl_down(sq, off, 64);
  }
  __shared__ float sh[2][4];
  const int lane = threadIdx.x & 63, w = threadIdx.x >> 6;
  if (lane == 0) { sh[0][w] = s; sh[1][w] = sq; }
  __syncthreads();
  if (threadIdx.x == 0) {
    float S = sh[0][0] + sh[0][1] + sh[0][2] + sh[0][3];
    float SQ = sh[1][0] + sh[1][1] + sh[1][2] + sh[1][3];
    float mu = S / rows;
    float var = SQ / rows - mu * mu;
    mv[c] = mu;
    mv[C + c] = rsqrtf(var + eps);
  }
}

// In-place BN(train)+ReLU for two tensors; half 1 optionally also writes its
// transposed copy (for embed_v^T). grid = (nblk, 2).
__global__ void bn_apply2(float* X0, float* X1,
                          const float* __restrict__ mv0, const float* __restrict__ mv1,
                          const float* __restrict__ g0, const float* __restrict__ b0,
                          const float* __restrict__ g1, const float* __restrict__ b1,
                          int rows, int C, float* XT1) {
  const int z = blockIdx.y;
  float* X = z ? X1 : X0;
  const float* mv = z ? mv1 : mv0;
  const float* gg = z ? g1 : g0;
  const float* bb = z ? b1 : b0;
  const long total = (long)rows * C;
  for (long i = (long)blockIdx.x * blockDim.x + threadIdx.x; i < total;
       i += (long)gridDim.x * blockDim.x) {
    int c = (int)(i % C);
    float v = fmaxf((X[i] - mv[c]) * mv[C + c] * gg[c] + bb[c], 0.f);
    X[i] = v;
    if (XT1 && z) {
      int r = (int)(i / C);
      XT1[(long)c * rows + r] = v;
    }
  }
}

// Builds cat = [hidden(R,rows,H) as (rows, R*H) | pre(R,rows,H) as (rows, R*H) | side(rows,SH)]
__global__ void concat2(const float* __restrict__ hidU, const float* __restrict__ huPre,
                        const float* __restrict__ sideU,
                        const float* __restrict__ hidV, const float* __restrict__ hvPre,
                        const float* __restrict__ sideV,
                        float* catU, float* catV, int rows) {
  const int z = blockIdx.y;
  const float* hid = z ? hidV : hidU;
  const float* pre = z ? hvPre : huPre;
  const float* side = z ? sideV : sideU;
  float* cat = z ? catV : catU;
  const long total = (long)rows * CAT_DIM;
  for (long i = (long)blockIdx.x * blockDim.x + threadIdx.x; i < total;
       i += (long)gridDim.x * blockDim.x) {
    int u = (int)(i / CAT_DIM);
    int j = (int)(i % CAT_DIM);
    float v;
    if (j < R_DIM * H_DIM) {
      v = hid[(long)(j >> 6) * rows * H_DIM + (long)u * H_DIM + (j & 63)];
    } else if (j < 2 * R_DIM * H_DIM) {
      int jj = j - R_DIM * H_DIM;
      v = pre[(long)(jj >> 6) * rows * H_DIM + (long)u * H_DIM + (jj & 63)];
    } else {
      v = side[(long)u * SH_DIM + (j - 2 * R_DIM * H_DIM)];
    }
    cat[i] = v;
  }
}

extern "C" void kernel_launch(void* const* d_in, const int* in_sizes, int n_in,
                              void* d_out, int out_size, void* d_ws, size_t ws_size,
                              hipStream_t stream) {
  (void)in_sizes; (void)n_in; (void)out_size; (void)ws_size;
  const float* feature_u   = (const float*)d_in[0];
  const float* feature_v   = (const float*)d_in[1];
  const float* M_u         = (const float*)d_in[2];
  const float* M_v         = (const float*)d_in[3];
  const float* W           = (const float*)d_in[4];
  const float* Q           = (const float*)d_in[5];
  const float* side_u_f    = (const float*)d_in[6];
  const float* side_v_f    = (const float*)d_in[7];
  const float* w_side_u    = (const float*)d_in[8];
  const float* b_side_u    = (const float*)d_in[9];
  const float* g_side_u    = (const float*)d_in[10];
  const float* beta_side_u = (const float*)d_in[11];
  const float* w_side_v    = (const float*)d_in[12];
  const float* b_side_v    = (const float*)d_in[13];
  const float* g_side_v    = (const float*)d_in[14];
  const float* beta_side_v = (const float*)d_in[15];
  const float* w_cat_u     = (const float*)d_in[16];
  const float* b_cat_u     = (const float*)d_in[17];
  const float* g_cat_u     = (const float*)d_in[18];
  const float* beta_cat_u  = (const float*)d_in[19];
  const float* w_cat_v     = (const float*)d_in[20];
  const float* b_cat_v     = (const float*)d_in[21];
  const float* g_cat_v     = (const float*)d_in[22];
  const float* beta_cat_v  = (const float*)d_in[23];
  float* out = (float*)d_out;

  float* ws = (float*)d_ws;
  long off = 0;
  float* hv_pre   = ws + off; off += (long)R_DIM * V_DIM * H_DIM;   // 640000
  float* hu_pre   = ws + off; off += (long)R_DIM * U_DIM * H_DIM;
  float* hidden_u = ws + off; off += (long)R_DIM * U_DIM * H_DIM;
  float* hidden_v = ws + off; off += (long)R_DIM * V_DIM * H_DIM;
  float* sideU    = ws + off; off += (long)U_DIM * SH_DIM;
  float* sideV    = ws + off; off += (long)V_DIM * SH_DIM;
  float* catU     = ws + off; off += (long)U_DIM * CAT_DIM;
  float* catV     = ws + off; off += (long)V_DIM * CAT_DIM;
  float* preU     = ws + off; off += (long)U_DIM * O_DIM;
  float* preV     = ws + off; off += (long)V_DIM * O_DIM;
  float* evT      = ws + off; off += (long)O_DIM * V_DIM;
  float* AQ       = ws + off; off += (long)R_DIM * U_DIM * O_DIM;
  float* mvSideU  = ws + off; off += 2 * SH_DIM;
  float* mvSideV  = ws + off; off += 2 * SH_DIM;
  float* mvCatU   = ws + off; off += 2 * O_DIM + 2;
  float* mvCatV   = ws + off; off += 2 * O_DIM + 2;
  (void)off;  // ~27.3 MB of ws

  dim3 blk(256);

  // Stage A: hv_pre[r] = feature_v @ W[r]; hu_pre[r] = feature_u @ W[r]
  {
    GemmArgs g{};
    g.A0 = feature_v; g.B0 = W; g.bias0 = nullptr; g.C0 = hv_pre;
    g.A1 = feature_u; g.B1 = W; g.bias1 = nullptr; g.C1 = hu_pre;
    g.sA = 0; g.sB = (long)F_DIM * H_DIM; g.sC = (long)V_DIM * H_DIM;
    g.zSplit = R_DIM; g.M = V_DIM; g.N = H_DIM; g.K = F_DIM;
    gemm_nn<2, false, false><<<dim3(63, 1, 2 * R_DIM), blk, 0, stream>>>(g);
  }
  // Side pre: side = side_feature @ w_side + b_side
  {
    GemmArgs g{};
    g.A0 = side_u_f; g.B0 = w_side_u; g.bias0 = b_side_u; g.C0 = sideU;
    g.A1 = side_v_f; g.B1 = w_side_v; g.bias1 = b_side_v; g.C1 = sideV;
    g.sA = 0; g.sB = 0; g.sC = 0;
    g.zSplit = 1; g.M = U_DIM; g.N = SH_DIM; g.K = SF_DIM;
    gemm_nn<2, false, true><<<dim3(63, 1, 2), blk, 0, stream>>>(g);
  }
  // Stage B: hidden_u[r] = relu(M_u[r] @ hv_pre[r]); hidden_v[r] = relu(M_v[r] @ hu_pre[r])
  {
    GemmArgs g{};
    g.A0 = M_u; g.B0 = hv_pre; g.bias0 = nullptr; g.C0 = hidden_u;
    g.A1 = M_v; g.B1 = hu_pre; g.bias1 = nullptr; g.C1 = hidden_v;
    g.sA = (long)U_DIM * V_DIM; g.sB = (long)V_DIM * H_DIM; g.sC = (long)U_DIM * H_DIM;
    g.zSplit = R_DIM; g.M = U_DIM; g.N = H_DIM; g.K = V_DIM;
    gemm_nn<2, true, false><<<dim3(63, 1, 2 * R_DIM), blk, 0, stream>>>(g);
  }
  // Side BN + ReLU (in place)
  colstats2<<<dim3(SH_DIM, 2), blk, 0, stream>>>(sideU, sideV, U_DIM, SH_DIM,
                                                 mvSideU, mvSideV, 1e-5f);
  bn_apply2<<<dim3(500, 2), blk, 0, stream>>>(sideU, sideV, mvSideU, mvSideV,
                                              g_side_u, beta_side_u, g_side_v, beta_side_v,
                                              U_DIM, SH_DIM, nullptr);
  // cat = [hidden | pre | side]   (feature@W_flat == pre, reused, no recompute)
  concat2<<<dim3(5500, 2), blk, 0, stream>>>(hidden_u, hu_pre, sideU,
                                             hidden_v, hv_pre, sideV, catU, catV, U_DIM);
  // cat GEMM: pre = cat @ w_cat + b_cat
  {
    GemmArgs g{};
    g.A0 = catU; g.B0 = w_cat_u; g.bias0 = b_cat_u; g.C0 = preU;
    g.A1 = catV; g.B1 = w_cat_v; g.bias1 = b_cat_v; g.C1 = preV;
    g.sA = 0; g.sB = 0; g.sC = 0;
    g.zSplit = 1; g.M = U_DIM; g.N = O_DIM; g.K = CAT_DIM;
    gemm_nn<2, false, true><<<dim3(63, 2, 2), blk, 0, stream>>>(g);
  }
  // cat BN + ReLU -> embed (in place); v-half also writes evT = embed_v^T
  colstats2<<<dim3(O_DIM, 2), blk, 0, stream>>>(preU, preV, U_DIM, O_DIM,
                                                mvCatU, mvCatV, 1e-5f);
  bn_apply2<<<dim3(586, 2), blk, 0, stream>>>(preU, preV, mvCatU, mvCatV,
                                              g_cat_u, beta_cat_u, g_cat_v, beta_cat_v,
                                              U_DIM, O_DIM, evT);
  // E1: AQ[r] = embed_u @ Q[r]
  {
    GemmArgs g{};
    g.A0 = preU; g.B0 = Q; g.bias0 = nullptr; g.C0 = AQ;
    g.A1 = preU; g.B1 = Q; g.bias1 = nullptr; g.C1 = AQ;
    g.sA = 0; g.sB = (long)O_DIM * O_DIM; g.sC = (long)U_DIM * O_DIM;
    g.zSplit = R_DIM; g.M = U_DIM; g.N = O_DIM; g.K = O_DIM;
    gemm_nn<2, false, false><<<dim3(63, 2, R_DIM), blk, 0, stream>>>(g);
  }
  // E2: score[r] = AQ[r] @ embed_v^T   (NN with evT, fully coalesced)
  {
    GemmArgs g{};
    g.A0 = AQ; g.B0 = evT; g.bias0 = nullptr; g.C0 = out;
    g.A1 = AQ; g.B1 = evT; g.bias1 = nullptr; g.C1 = out;
    g.sA = (long)U_DIM * O_DIM; g.sB = 0; g.sC = (long)U_DIM * V_DIM;
    g.zSplit = R_DIM; g.M = U_DIM; g.N = V_DIM; g.K = O_DIM;
    gemm_nn<4, false, false><<<dim3(32, 32, R_DIM), blk, 0, stream>>>(g);
  }
}

// Round 3
// 566.357 us; speedup vs baseline: 1.8741x; 1.8741x over previous
//
#include <hip/hip_runtime.h>

#define U_DIM 2000
#define V_DIM 2000
#define F_DIM 2000
#define R_DIM 5
#define H_DIM 64
#define O_DIM 75
#define SH_DIM 64
#define SF_DIM 128
#define CAT_DIM (2 * R_DIM * H_DIM + SH_DIM) /* 704 */

struct G2 {
  const float* A0; const float* B0; float* C0;
  const float* A1; const float* B1; float* C1;
  long sA0, sB0, sC0, sA1, sB1, sC1;
  int zSplit, M, N, K;
};

// C = A[M,K] @ B[K,N], row-major. 256 threads, BM=BN=64, BK=16, 4x4 per thread.
// KSPLIT: blockIdx.y = K-chunk index, C is a partial buffer [ks][z][M][N]
//         (kernel adds ks * gridDim.z * M * N).
// else:   blockIdx.y = column-block index.
// Biases are never needed (Linear bias cancels inside train-mode BatchNorm).
template<bool KSPLIT>
__launch_bounds__(256)
__global__ void gemm64(G2 g) {
  const int z = blockIdx.z;
  const float *A, *B;
  float* C;
  if (z < g.zSplit) {
    A = g.A0 + (long)z * g.sA0; B = g.B0 + (long)z * g.sB0; C = g.C0 + (long)z * g.sC0;
  } else {
    const int zi = z - g.zSplit;
    A = g.A1 + (long)zi * g.sA1; B = g.B1 + (long)zi * g.sB1; C = g.C1 + (long)zi * g.sC1;
  }
  const int M = g.M, N = g.N, K = g.K;
  const int row0 = blockIdx.x << 6;
  int col0, kbeg, kend;
  if (KSPLIT) {
    col0 = 0;
    const int kch = (K + (int)gridDim.y - 1) / (int)gridDim.y;
    kbeg = (int)blockIdx.y * kch;
    kend = min(K, kbeg + kch);
    C += (long)blockIdx.y * (long)gridDim.z * (long)M * N;
  } else {
    col0 = (int)blockIdx.y << 6;
    kbeg = 0; kend = K;
  }

  __shared__ float As[16][68];  // transposed: As[k][m], +4 pad
  __shared__ float Bs[16][64];

  const int tid = threadIdx.x;
  const int ar = tid >> 2, ak4 = (tid & 3) << 2;   // A staging: row, k-quad
  const int bk = tid >> 4, bn4 = (tid & 15) << 2;  // B staging: k, col-quad
  const int tx = tid & 15, ty = tid >> 4;

  const bool arow_ok = (row0 + ar) < M;
  const long Arow = (long)(row0 + ar) * K;
  const bool avec = ((K & 3) == 0);
  const bool bvec = ((N & 3) == 0);

  float acc[4][4];
#pragma unroll
  for (int i = 0; i < 4; ++i)
#pragma unroll
    for (int j = 0; j < 4; ++j) acc[i][j] = 0.f;

  for (int k0 = kbeg; k0 < kend; k0 += 16) {
    // ---- stage A tile (64 rows x 16 k), one float4 per thread, transposed store
    {
      const int gk = k0 + ak4;
      float4 a4;
      if (arow_ok && avec && gk + 3 < kend) {
        a4 = *reinterpret_cast<const float4*>(A + Arow + gk);
      } else {
        a4.x = (arow_ok && gk + 0 < kend) ? A[Arow + gk + 0] : 0.f;
        a4.y = (arow_ok && gk + 1 < kend) ? A[Arow + gk + 1] : 0.f;
        a4.z = (arow_ok && gk + 2 < kend) ? A[Arow + gk + 2] : 0.f;
        a4.w = (arow_ok && gk + 3 < kend) ? A[Arow + gk + 3] : 0.f;
      }
      As[ak4 + 0][ar] = a4.x;
      As[ak4 + 1][ar] = a4.y;
      As[ak4 + 2][ar] = a4.z;
      As[ak4 + 3][ar] = a4.w;
    }
    // ---- stage B tile (16 k x 64 cols), one float4 per thread
    {
      const int gkb = k0 + bk, gn = col0 + bn4;
      float4 b4;
      if (gkb < kend && bvec && gn + 3 < N) {
        b4 = *reinterpret_cast<const float4*>(B + (long)gkb * N + gn);
      } else {
        const long rb = (long)gkb * N;
        b4.x = (gkb < kend && gn + 0 < N) ? B[rb + gn + 0] : 0.f;
        b4.y = (gkb < kend && gn + 1 < N) ? B[rb + gn + 1] : 0.f;
        b4.z = (gkb < kend && gn + 2 < N) ? B[rb + gn + 2] : 0.f;
        b4.w = (gkb < kend && gn + 3 < N) ? B[rb + gn + 3] : 0.f;
      }
      *reinterpret_cast<float4*>(&Bs[bk][bn4]) = b4;
    }
    __syncthreads();
#pragma unroll
    for (int k = 0; k < 16; ++k) {
      const float4 av = *reinterpret_cast<const float4*>(&As[k][ty << 2]);
      const float4 bv = *reinterpret_cast<const float4*>(&Bs[k][tx << 2]);
      const float aa[4] = {av.x, av.y, av.z, av.w};
      const float bb[4] = {bv.x, bv.y, bv.z, bv.w};
#pragma unroll
      for (int i = 0; i < 4; ++i)
#pragma unroll
        for (int j = 0; j < 4; ++j) acc[i][j] = fmaf(aa[i], bb[j], acc[i][j]);
    }
    __syncthreads();
  }

  const int c0 = col0 + (tx << 2);
#pragma unroll
  for (int i = 0; i < 4; ++i) {
    const int r = row0 + (ty << 2) + i;
    if (r >= M) continue;
    if (bvec && c0 + 3 < N) {
      float4 v;
      v.x = acc[i][0]; v.y = acc[i][1]; v.z = acc[i][2]; v.w = acc[i][3];
      *reinterpret_cast<float4*>(C + (long)r * N + c0) = v;
    } else {
#pragma unroll
      for (int j = 0; j < 4; ++j)
        if (c0 + j < N) C[(long)r * N + c0 + j] = acc[i][j];
    }
  }
}

// out[i] = (relu?) sum_ks P[ks*stride + i]; float4-vectorized.
__global__ void reduceKS(const float* __restrict__ P, float* __restrict__ out,
                         long n4, long stride4, int KS, int relu) {
  const float4* p = reinterpret_cast<const float4*>(P);
  float4* o = reinterpret_cast<float4*>(out);
  for (long i = (long)blockIdx.x * blockDim.x + threadIdx.x; i < n4;
       i += (long)gridDim.x * blockDim.x) {
    float4 s = p[i];
    for (int ks = 1; ks < KS; ++ks) {
      float4 t = p[i + (long)ks * stride4];
      s.x += t.x; s.y += t.y; s.z += t.z; s.w += t.w;
    }
    if (relu) {
      s.x = fmaxf(s.x, 0.f); s.y = fmaxf(s.y, 0.f);
      s.z = fmaxf(s.z, 0.f); s.w = fmaxf(s.w, 0.f);
    }
    o[i] = s;
  }
}

// Column mean / rstd for two [rows, C] tensors (biased variance, BN train mode).
// mv layout: mv[0..C) = mean, mv[C..2C) = rsqrt(var + eps). grid = (C, 2).
__global__ void colstats2(const float* __restrict__ X0, const float* __restrict__ X1,
                          int rows, int C, float* mv0, float* mv1, float eps) {
  const float* X = blockIdx.y ? X1 : X0;
  float* mv = blockIdx.y ? mv1 : mv0;
  const int c = blockIdx.x;
  float s = 0.f, sq = 0.f;
  for (int r = threadIdx.x; r < rows; r += 256) {
    float x = X[(long)r * C + c];
    s += x;
    sq += x * x;
  }
#pragma unroll
  for (int off = 32; off > 0; off >>= 1) {
    s += __shfl_down(s, off, 64);
    sq += __shfl_down(sq, off, 64);
  }
  __shared__ float sh[2][4];
  const int lane = threadIdx.x & 63, w = threadIdx.x >> 6;
  if (lane == 0) { sh[0][w] = s; sh[1][w] = sq; }
  __syncthreads();
  if (threadIdx.x == 0) {
    float S = sh[0][0] + sh[0][1] + sh[0][2] + sh[0][3];
    float SQ = sh[1][0] + sh[1][1] + sh[1][2] + sh[1][3];
    float mu = S / rows;
    float var = SQ / rows - mu * mu;
    mv[c] = mu;
    mv[C + c] = rsqrtf(var + eps);
  }
}

// In-place BN(train)+ReLU for two tensors; half 1 optionally also writes its
// transposed copy (for embed_v^T). grid = (nblk, 2).
__global__ void bn_apply2(float* X0, float* X1,
                          const float* __restrict__ mv0, const float* __restrict__ mv1,
                          const float* __restrict__ g0, const float* __restrict__ b0,
                          const float* __restrict__ g1, const float* __restrict__ b1,
                          int rows, int C, float* XT1) {
  const int z = blockIdx.y;
  float* X = z ? X1 : X0;
  const float* mv = z ? mv1 : mv0;
  const float* gg = z ? g1 : g0;
  const float* bb = z ? b1 : b0;
  const long total = (long)rows * C;
  for (long i = (long)blockIdx.x * blockDim.x + threadIdx.x; i < total;
       i += (long)gridDim.x * blockDim.x) {
    int c = (int)(i % C);
    float v = fmaxf((X[i] - mv[c]) * mv[C + c] * gg[c] + bb[c], 0.f);
    X[i] = v;
    if (XT1 && z) {
      int r = (int)(i / C);
      XT1[(long)c * rows + r] = v;
    }
  }
}

// cat = [hidden(R,rows,H)->(rows,R*H) | pre(R,rows,H)->(rows,R*H) | side(rows,SH)]
__global__ void concat2(const float* __restrict__ hidU, const float* __restrict__ huPre,
                        const float* __restrict__ sideU,
                        const float* __restrict__ hidV, const float* __restrict__ hvPre,
                        const float* __restrict__ sideV,
                        float* catU, float* catV, int rows) {
  const int z = blockIdx.y;
  const float* hid = z ? hidV : hidU;
  const float* pre = z ? hvPre : huPre;
  const float* side = z ? sideV : sideU;
  float* cat = z ? catV : catU;
  const long total = (long)rows * CAT_DIM;
  for (long i = (long)blockIdx.x * blockDim.x + threadIdx.x; i < total;
       i += (long)gridDim.x * blockDim.x) {
    int u = (int)(i / CAT_DIM);
    int j = (int)(i % CAT_DIM);
    float v;
    if (j < R_DIM * H_DIM) {
      v = hid[(long)(j >> 6) * rows * H_DIM + (long)u * H_DIM + (j & 63)];
    } else if (j < 2 * R_DIM * H_DIM) {
      int jj = j - R_DIM * H_DIM;
      v = pre[(long)(jj >> 6) * rows * H_DIM + (long)u * H_DIM + (jj & 63)];
    } else {
      v = side[(long)u * SH_DIM + (j - 2 * R_DIM * H_DIM)];
    }
    cat[i] = v;
  }
}

extern "C" void kernel_launch(void* const* d_in, const int* in_sizes, int n_in,
                              void* d_out, int out_size, void* d_ws, size_t ws_size,
                              hipStream_t stream) {
  (void)in_sizes; (void)n_in; (void)out_size;
  const float* feature_u   = (const float*)d_in[0];
  const float* feature_v   = (const float*)d_in[1];
  const float* M_u         = (const float*)d_in[2];
  const float* M_v         = (const float*)d_in[3];
  const float* W           = (const float*)d_in[4];
  const float* Q           = (const float*)d_in[5];
  const float* side_u_f    = (const float*)d_in[6];
  const float* side_v_f    = (const float*)d_in[7];
  const float* w_side_u    = (const float*)d_in[8];
  const float* g_side_u    = (const float*)d_in[10];
  const float* beta_side_u = (const float*)d_in[11];
  const float* w_side_v    = (const float*)d_in[12];
  const float* g_side_v    = (const float*)d_in[14];
  const float* beta_side_v = (const float*)d_in[15];
  const float* w_cat_u     = (const float*)d_in[16];
  const float* g_cat_u     = (const float*)d_in[18];
  const float* beta_cat_u  = (const float*)d_in[19];
  const float* w_cat_v     = (const float*)d_in[20];
  const float* g_cat_v     = (const float*)d_in[22];
  const float* beta_cat_v  = (const float*)d_in[23];
  float* out = (float*)d_out;

  float* ws = (float*)d_ws;
  long off = 0;
  float* hv_pre   = ws + off; off += (long)R_DIM * V_DIM * H_DIM;  // followed by hu_pre (contiguous)
  float* hu_pre   = ws + off; off += (long)R_DIM * U_DIM * H_DIM;
  float* hidden_u = ws + off; off += (long)R_DIM * U_DIM * H_DIM;  // followed by hidden_v
  float* hidden_v = ws + off; off += (long)R_DIM * V_DIM * H_DIM;
  float* sideU    = ws + off; off += (long)U_DIM * SH_DIM;
  float* sideV    = ws + off; off += (long)V_DIM * SH_DIM;
  float* catU     = ws + off; off += (long)U_DIM * CAT_DIM;
  float* catV     = ws + off; off += (long)V_DIM * CAT_DIM;
  float* preU     = ws + off; off += (long)U_DIM * O_DIM;
  float* preV     = ws + off; off += (long)V_DIM * O_DIM;
  float* evT      = ws + off; off += (long)O_DIM * V_DIM;
  float* AQ       = ws + off; off += (long)R_DIM * U_DIM * O_DIM;
  float* mvSideU  = ws + off; off += 2 * SH_DIM;
  float* mvSideV  = ws + off; off += 2 * SH_DIM;
  float* mvCatU   = ws + off; off += 2 * O_DIM + 2;
  float* mvCatV   = ws + off; off += 2 * O_DIM + 2;
  float* P        = ws + off;  // K-split partials, KS * 10 * 2000 * 64 floats

  const long SLOT = 10L * 2000 * 64;  // 1,280,000 elems per ks-slice
  const long avail = (long)(ws_size / sizeof(float));
  int KS = 4;
  if (off + 4L * SLOT > avail) KS = 2;
  if (off + (long)KS * SLOT > avail) KS = 1;

  dim3 blk(256);
  const long MN = 2000L * 64;

  // Stage A: P[ks][z] = feature_{v|u} @ W[r]  (z<5: v-side, z>=5: u-side)
  {
    G2 g{};
    g.A0 = feature_v; g.B0 = W; g.C0 = P;
    g.sA0 = 0; g.sB0 = (long)F_DIM * H_DIM; g.sC0 = MN;
    g.A1 = feature_u; g.B1 = W; g.C1 = P + 5 * MN;
    g.sA1 = 0; g.sB1 = (long)F_DIM * H_DIM; g.sC1 = MN;
    g.zSplit = R_DIM; g.M = 2000; g.N = H_DIM; g.K = F_DIM;
    gemm64<true><<<dim3(32, KS, 10), blk, 0, stream>>>(g);
  }
  reduceKS<<<1250, blk, 0, stream>>>(P, hv_pre, SLOT / 4, SLOT / 4, KS, 0);

  // Side: side = side_feature @ w_side  (bias cancels in BN)
  {
    G2 g{};
    g.A0 = side_u_f; g.B0 = w_side_u; g.C0 = sideU;
    g.sA0 = 0; g.sB0 = 0; g.sC0 = 0;
    g.A1 = side_v_f; g.B1 = w_side_v; g.C1 = sideV;
    g.sA1 = 0; g.sB1 = 0; g.sC1 = 0;
    g.zSplit = 1; g.M = U_DIM; g.N = SH_DIM; g.K = SF_DIM;
    gemm64<false><<<dim3(32, 1, 2), blk, 0, stream>>>(g);
  }

  // Stage B: P[ks][z] = M_{u|v}[r] @ {hv|hu}_pre[r]
  {
    G2 g{};
    g.A0 = M_u; g.B0 = hv_pre; g.C0 = P;
    g.sA0 = (long)U_DIM * V_DIM; g.sB0 = MN; g.sC0 = MN;
    g.A1 = M_v; g.B1 = hu_pre; g.C1 = P + 5 * MN;
    g.sA1 = (long)V_DIM * U_DIM; g.sB1 = MN; g.sC1 = MN;
    g.zSplit = R_DIM; g.M = 2000; g.N = H_DIM; g.K = 2000;
    gemm64<true><<<dim3(32, KS, 10), blk, 0, stream>>>(g);
  }
  reduceKS<<<1250, blk, 0, stream>>>(P, hidden_u, SLOT / 4, SLOT / 4, KS, 1);

  // Side BN + ReLU (in place)
  colstats2<<<dim3(SH_DIM, 2), blk, 0, stream>>>(sideU, sideV, U_DIM, SH_DIM,
                                                 mvSideU, mvSideV, 1e-5f);
  bn_apply2<<<dim3(500, 2), blk, 0, stream>>>(sideU, sideV, mvSideU, mvSideV,
                                              g_side_u, beta_side_u, g_side_v, beta_side_v,
                                              U_DIM, SH_DIM, nullptr);
  // cat = [hidden | pre | side]
  concat2<<<dim3(5500, 2), blk, 0, stream>>>(hidden_u, hu_pre, sideU,
                                             hidden_v, hv_pre, sideV, catU, catV, U_DIM);
  // cat GEMM: pre = cat @ w_cat
  {
    G2 g{};
    g.A0 = catU; g.B0 = w_cat_u; g.C0 = preU;
    g.sA0 = 0; g.sB0 = 0; g.sC0 = 0;
    g.A1 = catV; g.B1 = w_cat_v; g.C1 = preV;
    g.sA1 = 0; g.sB1 = 0; g.sC1 = 0;
    g.zSplit = 1; g.M = U_DIM; g.N = O_DIM; g.K = CAT_DIM;
    gemm64<false><<<dim3(32, 2, 2), blk, 0, stream>>>(g);
  }
  // cat BN + ReLU -> embed (in place); v-half also writes evT = embed_v^T
  colstats2<<<dim3(O_DIM, 2), blk, 0, stream>>>(preU, preV, U_DIM, O_DIM,
                                                mvCatU, mvCatV, 1e-5f);
  bn_apply2<<<dim3(586, 2), blk, 0, stream>>>(preU, preV, mvCatU, mvCatV,
                                              g_cat_u, beta_cat_u, g_cat_v, beta_cat_v,
                                              U_DIM, O_DIM, evT);
  // E1: AQ[r] = embed_u @ Q[r]
  {
    G2 g{};
    g.A0 = preU; g.B0 = Q; g.C0 = AQ;
    g.sA0 = 0; g.sB0 = (long)O_DIM * O_DIM; g.sC0 = (long)U_DIM * O_DIM;
    g.A1 = preU; g.B1 = Q; g.C1 = AQ;
    g.sA1 = 0; g.sB1 = (long)O_DIM * O_DIM; g.sC1 = (long)U_DIM * O_DIM;
    g.zSplit = R_DIM; g.M = U_DIM; g.N = O_DIM; g.K = O_DIM;
    gemm64<false><<<dim3(32, 2, R_DIM), blk, 0, stream>>>(g);
  }
  // E2: score[r] = AQ[r] @ embed_v^T (via evT, NN, coalesced)
  {
    G2 g{};
    g.A0 = AQ; g.B0 = evT; g.C0 = out;
    g.sA0 = (long)U_DIM * O_DIM; g.sB0 = 0; g.sC0 = (long)U_DIM * V_DIM;
    g.A1 = AQ; g.B1 = evT; g.C1 = out;
    g.sA1 = (long)U_DIM * O_DIM; g.sB1 = 0; g.sC1 = (long)U_DIM * V_DIM;
    g.zSplit = R_DIM; g.M = U_DIM; g.N = V_DIM; g.K = O_DIM;
    gemm64<false><<<dim3(32, 32, R_DIM), blk, 0, stream>>>(g);
  }
}

// Round 4
// 495.327 us; speedup vs baseline: 2.1428x; 1.1434x over previous
//
#include <hip/hip_runtime.h>

#define U_DIM 2000
#define V_DIM 2000
#define F_DIM 2000
#define R_DIM 5
#define H_DIM 64
#define O_DIM 75
#define SH_DIM 64
#define SF_DIM 128
#define CAT_DIM (2 * R_DIM * H_DIM + SH_DIM) /* 704 */

typedef __attribute__((ext_vector_type(8))) short bf16x8;
typedef __attribute__((ext_vector_type(4))) float f32x4;

struct G2 {
  const float* A0; const float* B0; float* C0;
  const float* A1; const float* B1; float* C1;
  long sA0, sB0, sC0, sA1, sB1, sC1;
  int zSplit, M, N, K;
};

// Split x into bf16 hi (truncate) + bf16 lo (residual, truncated); pack pairs.
__device__ inline void split2(float x0, float x1, unsigned& h, unsigned& l) {
  unsigned u0 = __float_as_uint(x0), u1 = __float_as_uint(x1);
  unsigned h0 = u0 & 0xffff0000u, h1 = u1 & 0xffff0000u;
  h = (u0 >> 16) | h1;
  unsigned l0 = __float_as_uint(x0 - __uint_as_float(h0));
  unsigned l1 = __float_as_uint(x1 - __uint_as_float(h1));
  l = (l0 >> 16) | (l1 & 0xffff0000u);
}

// C = A[M,K] @ B[K,N] in split-bf16 MFMA (AhBh + AhBl + AlBh), fp32 accum.
// Block = 256 thr = 4 waves; tile 64x64, BK=32. Wave w owns rows [16w,16w+16).
// LDS stored in fragment order: [tile][lane][8 bf16] -> lane-linear ds_read_b128.
// KSPLIT: blockIdx.y = K-chunk; C = partials [ks][z][M][N]. else blockIdx.y = col-block.
template<bool KSPLIT>
__launch_bounds__(256)
__global__ void mfma_gemm(G2 g) {
  const int z = blockIdx.z;
  const float *A, *B; float* C;
  if (z < g.zSplit) {
    A = g.A0 + (long)z * g.sA0; B = g.B0 + (long)z * g.sB0; C = g.C0 + (long)z * g.sC0;
  } else {
    const int zi = z - g.zSplit;
    A = g.A1 + (long)zi * g.sA1; B = g.B1 + (long)zi * g.sB1; C = g.C1 + (long)zi * g.sC1;
  }
  const int M = g.M, N = g.N, K = g.K;
  const int row0 = blockIdx.x << 6;
  int col0, kbeg, kend;
  if (KSPLIT) {
    col0 = 0;
    const int kch = (K + (int)gridDim.y - 1) / (int)gridDim.y;
    kbeg = (int)blockIdx.y * kch;
    kend = min(K, kbeg + kch);
    C += (long)blockIdx.y * (long)gridDim.z * (long)M * N;
  } else {
    col0 = (int)blockIdx.y << 6;
    kbeg = 0; kend = K;
  }

  __shared__ short Ah[4][64][8], Al[4][64][8], Bh[4][64][8], Bl[4][64][8];

  const int tid = threadIdx.x;
  const int lane = tid & 63;
  const int w = tid >> 6;
  const bool kvec = ((K & 3) == 0);

  f32x4 acc[4];
#pragma unroll
  for (int c = 0; c < 4; ++c) acc[c] = (f32x4){0.f, 0.f, 0.f, 0.f};

  for (int k0 = kbeg; k0 < kend; k0 += 32) {
    // ---- stage A tile (64 rows x 32 k): 2 quads/thread along k, float4 loads
#pragma unroll
    for (int q = 0; q < 2; ++q) {
      const int r = (tid >> 3) + (q << 5);
      const int kq = (tid & 7) << 2;
      const int gr = row0 + r, gk = k0 + kq;
      float x0, x1, x2, x3;
      if (gr < M && kvec && gk + 3 < kend) {
        const float4 f = *reinterpret_cast<const float4*>(A + (long)gr * K + gk);
        x0 = f.x; x1 = f.y; x2 = f.z; x3 = f.w;
      } else {
        const long rb = (long)gr * K;
        x0 = (gr < M && gk + 0 < kend) ? A[rb + gk + 0] : 0.f;
        x1 = (gr < M && gk + 1 < kend) ? A[rb + gk + 1] : 0.f;
        x2 = (gr < M && gk + 2 < kend) ? A[rb + gk + 2] : 0.f;
        x3 = (gr < M && gk + 3 < kend) ? A[rb + gk + 3] : 0.f;
      }
      unsigned h01, l01, h23, l23;
      split2(x0, x1, h01, l01);
      split2(x2, x3, h23, l23);
      const int t = r >> 4, ln = (r & 15) + (((kq >> 3) & 3) << 4), j0 = kq & 7;
      uint2 hv; hv.x = h01; hv.y = h23;
      uint2 lv; lv.x = l01; lv.y = l23;
      *reinterpret_cast<uint2*>(&Ah[t][ln][j0]) = hv;
      *reinterpret_cast<uint2*>(&Al[t][ln][j0]) = lv;
    }
    // ---- stage B tile (32 k x 64 cols): 2 quads/thread along k (fixed n)
#pragma unroll
    for (int q = 0; q < 2; ++q) {
      const int n = tid & 63;
      const int kq = ((tid >> 6) + (q << 2)) << 2;
      const int gn = col0 + n;
      float xb[4];
#pragma unroll
      for (int i2 = 0; i2 < 4; ++i2) {
        const int gk = k0 + kq + i2;
        xb[i2] = (gk < kend && gn < N) ? B[(long)gk * N + gn] : 0.f;
      }
      unsigned h01, l01, h23, l23;
      split2(xb[0], xb[1], h01, l01);
      split2(xb[2], xb[3], h23, l23);
      const int c = n >> 4, ln = (((kq >> 3) & 3) << 4) + (n & 15), j0 = kq & 7;
      uint2 hv; hv.x = h01; hv.y = h23;
      uint2 lv; lv.x = l01; lv.y = l23;
      *reinterpret_cast<uint2*>(&Bh[c][ln][j0]) = hv;
      *reinterpret_cast<uint2*>(&Bl[c][ln][j0]) = lv;
    }
    __syncthreads();
    const bf16x8 ah = *reinterpret_cast<const bf16x8*>(&Ah[w][lane][0]);
    const bf16x8 al = *reinterpret_cast<const bf16x8*>(&Al[w][lane][0]);
#pragma unroll
    for (int c = 0; c < 4; ++c) {
      const bf16x8 bh = *reinterpret_cast<const bf16x8*>(&Bh[c][lane][0]);
      const bf16x8 bl = *reinterpret_cast<const bf16x8*>(&Bl[c][lane][0]);
      acc[c] = __builtin_amdgcn_mfma_f32_16x16x32_bf16(ah, bh, acc[c], 0, 0, 0);
      acc[c] = __builtin_amdgcn_mfma_f32_16x16x32_bf16(ah, bl, acc[c], 0, 0, 0);
      acc[c] = __builtin_amdgcn_mfma_f32_16x16x32_bf16(al, bh, acc[c], 0, 0, 0);
    }
    __syncthreads();
  }

  // C/D layout: col = lane&15, row = (lane>>4)*4 + reg   [m89-verified]
  const int rbase = (w << 4) + ((lane >> 4) << 2);
  const int cb = lane & 15;
#pragma unroll
  for (int c = 0; c < 4; ++c) {
    const int col = col0 + (c << 4) + cb;
    if (col >= N) continue;
#pragma unroll
    for (int i = 0; i < 4; ++i) {
      const int r = row0 + rbase + i;
      if (r < M) C[(long)r * N + col] = acc[c][i];
    }
  }
}

// fp32 fallback GEMM for the small stages (side / cat / E1). 64x64 tile, 4x4/thread.
__launch_bounds__(256)
__global__ void gemm64(G2 g) {
  const int z = blockIdx.z;
  const float *A, *B;
  float* C;
  if (z < g.zSplit) {
    A = g.A0 + (long)z * g.sA0; B = g.B0 + (long)z * g.sB0; C = g.C0 + (long)z * g.sC0;
  } else {
    const int zi = z - g.zSplit;
    A = g.A1 + (long)zi * g.sA1; B = g.B1 + (long)zi * g.sB1; C = g.C1 + (long)zi * g.sC1;
  }
  const int M = g.M, N = g.N, K = g.K;
  const int row0 = blockIdx.x << 6;
  const int col0 = (int)blockIdx.y << 6;

  __shared__ float As[16][68];
  __shared__ float Bs[16][64];

  const int tid = threadIdx.x;
  const int ar = tid >> 2, ak4 = (tid & 3) << 2;
  const int bk = tid >> 4, bn4 = (tid & 15) << 2;
  const int tx = tid & 15, ty = tid >> 4;

  const bool arow_ok = (row0 + ar) < M;
  const long Arow = (long)(row0 + ar) * K;
  const bool avec = ((K & 3) == 0);
  const bool bvec = ((N & 3) == 0);

  float acc[4][4];
#pragma unroll
  for (int i = 0; i < 4; ++i)
#pragma unroll
    for (int j = 0; j < 4; ++j) acc[i][j] = 0.f;

  for (int k0 = 0; k0 < K; k0 += 16) {
    {
      const int gk = k0 + ak4;
      float4 a4;
      if (arow_ok && avec && gk + 3 < K) {
        a4 = *reinterpret_cast<const float4*>(A + Arow + gk);
      } else {
        a4.x = (arow_ok && gk + 0 < K) ? A[Arow + gk + 0] : 0.f;
        a4.y = (arow_ok && gk + 1 < K) ? A[Arow + gk + 1] : 0.f;
        a4.z = (arow_ok && gk + 2 < K) ? A[Arow + gk + 2] : 0.f;
        a4.w = (arow_ok && gk + 3 < K) ? A[Arow + gk + 3] : 0.f;
      }
      As[ak4 + 0][ar] = a4.x;
      As[ak4 + 1][ar] = a4.y;
      As[ak4 + 2][ar] = a4.z;
      As[ak4 + 3][ar] = a4.w;
    }
    {
      const int gkb = k0 + bk, gn = col0 + bn4;
      float4 b4;
      if (gkb < K && bvec && gn + 3 < N) {
        b4 = *reinterpret_cast<const float4*>(B + (long)gkb * N + gn);
      } else {
        const long rb = (long)gkb * N;
        b4.x = (gkb < K && gn + 0 < N) ? B[rb + gn + 0] : 0.f;
        b4.y = (gkb < K && gn + 1 < N) ? B[rb + gn + 1] : 0.f;
        b4.z = (gkb < K && gn + 2 < N) ? B[rb + gn + 2] : 0.f;
        b4.w = (gkb < K && gn + 3 < N) ? B[rb + gn + 3] : 0.f;
      }
      *reinterpret_cast<float4*>(&Bs[bk][bn4]) = b4;
    }
    __syncthreads();
#pragma unroll
    for (int k = 0; k < 16; ++k) {
      const float4 av = *reinterpret_cast<const float4*>(&As[k][ty << 2]);
      const float4 bv = *reinterpret_cast<const float4*>(&Bs[k][tx << 2]);
      const float aa[4] = {av.x, av.y, av.z, av.w};
      const float bb[4] = {bv.x, bv.y, bv.z, bv.w};
#pragma unroll
      for (int i = 0; i < 4; ++i)
#pragma unroll
        for (int j = 0; j < 4; ++j) acc[i][j] = fmaf(aa[i], bb[j], acc[i][j]);
    }
    __syncthreads();
  }

  const int c0 = col0 + (tx << 2);
#pragma unroll
  for (int i = 0; i < 4; ++i) {
    const int r = row0 + (ty << 2) + i;
    if (r >= M) continue;
    if (bvec && c0 + 3 < N) {
      float4 v;
      v.x = acc[i][0]; v.y = acc[i][1]; v.z = acc[i][2]; v.w = acc[i][3];
      *reinterpret_cast<float4*>(C + (long)r * N + c0) = v;
    } else {
#pragma unroll
      for (int j = 0; j < 4; ++j)
        if (c0 + j < N) C[(long)r * N + c0 + j] = acc[i][j];
    }
  }
}

// out[i] = (relu?) sum_ks P[ks*stride + i]; float4-vectorized.
__global__ void reduceKS(const float* __restrict__ P, float* __restrict__ out,
                         long n4, long stride4, int KS, int relu) {
  const float4* p = reinterpret_cast<const float4*>(P);
  float4* o = reinterpret_cast<float4*>(out);
  for (long i = (long)blockIdx.x * blockDim.x + threadIdx.x; i < n4;
       i += (long)gridDim.x * blockDim.x) {
    float4 s = p[i];
    for (int ks = 1; ks < KS; ++ks) {
      float4 t = p[i + (long)ks * stride4];
      s.x += t.x; s.y += t.y; s.z += t.z; s.w += t.w;
    }
    if (relu) {
      s.x = fmaxf(s.x, 0.f); s.y = fmaxf(s.y, 0.f);
      s.z = fmaxf(s.z, 0.f); s.w = fmaxf(s.w, 0.f);
    }
    o[i] = s;
  }
}

// Column mean / rstd (biased var, BN train). mv: [0..C)=mean, [C..2C)=rsqrt(var+eps).
__global__ void colstats2(const float* __restrict__ X0, const float* __restrict__ X1,
                          int rows, int C, float* mv0, float* mv1, float eps) {
  const float* X = blockIdx.y ? X1 : X0;
  float* mv = blockIdx.y ? mv1 : mv0;
  const int c = blockIdx.x;
  float s = 0.f, sq = 0.f;
  for (int r = threadIdx.x; r < rows; r += 256) {
    float x = X[(long)r * C + c];
    s += x;
    sq += x * x;
  }
#pragma unroll
  for (int off = 32; off > 0; off >>= 1) {
    s += __shfl_down(s, off, 64);
    sq += __shfl_down(sq, off, 64);
  }
  __shared__ float sh[2][4];
  const int lane = threadIdx.x & 63, w = threadIdx.x >> 6;
  if (lane == 0) { sh[0][w] = s; sh[1][w] = sq; }
  __syncthreads();
  if (threadIdx.x == 0) {
    float S = sh[0][0] + sh[0][1] + sh[0][2] + sh[0][3];
    float SQ = sh[1][0] + sh[1][1] + sh[1][2] + sh[1][3];
    float mu = S / rows;
    float var = SQ / rows - mu * mu;
    mv[c] = mu;
    mv[C + c] = rsqrtf(var + eps);
  }
}

// In-place BN(train)+ReLU; half 1 optionally writes transposed copy (embed_v^T).
__global__ void bn_apply2(float* X0, float* X1,
                          const float* __restrict__ mv0, const float* __restrict__ mv1,
                          const float* __restrict__ g0, const float* __restrict__ b0,
                          const float* __restrict__ g1, const float* __restrict__ b1,
                          int rows, int C, float* XT1) {
  const int z = blockIdx.y;
  float* X = z ? X1 : X0;
  const float* mv = z ? mv1 : mv0;
  const float* gg = z ? g1 : g0;
  const float* bb = z ? b1 : b0;
  const long total = (long)rows * C;
  for (long i = (long)blockIdx.x * blockDim.x + threadIdx.x; i < total;
       i += (long)gridDim.x * blockDim.x) {
    int c = (int)(i % C);
    float v = fmaxf((X[i] - mv[c]) * mv[C + c] * gg[c] + bb[c], 0.f);
    X[i] = v;
    if (XT1 && z) {
      int r = (int)(i / C);
      XT1[(long)c * rows + r] = v;
    }
  }
}

// cat = [hidden(R,rows,H)->(rows,R*H) | pre(R,rows,H)->(rows,R*H) | side(rows,SH)]
__global__ void concat2(const float* __restrict__ hidU, const float* __restrict__ huPre,
                        const float* __restrict__ sideU,
                        const float* __restrict__ hidV, const float* __restrict__ hvPre,
                        const float* __restrict__ sideV,
                        float* catU, float* catV, int rows) {
  const int z = blockIdx.y;
  const float* hid = z ? hidV : hidU;
  const float* pre = z ? hvPre : huPre;
  const float* side = z ? sideV : sideU;
  float* cat = z ? catV : catU;
  const long total = (long)rows * CAT_DIM;
  for (long i = (long)blockIdx.x * blockDim.x + threadIdx.x; i < total;
       i += (long)gridDim.x * blockDim.x) {
    int u = (int)(i / CAT_DIM);
    int j = (int)(i % CAT_DIM);
    float v;
    if (j < R_DIM * H_DIM) {
      v = hid[(long)(j >> 6) * rows * H_DIM + (long)u * H_DIM + (j & 63)];
    } else if (j < 2 * R_DIM * H_DIM) {
      int jj = j - R_DIM * H_DIM;
      v = pre[(long)(jj >> 6) * rows * H_DIM + (long)u * H_DIM + (jj & 63)];
    } else {
      v = side[(long)u * SH_DIM + (j - 2 * R_DIM * H_DIM)];
    }
    cat[i] = v;
  }
}

extern "C" void kernel_launch(void* const* d_in, const int* in_sizes, int n_in,
                              void* d_out, int out_size, void* d_ws, size_t ws_size,
                              hipStream_t stream) {
  (void)in_sizes; (void)n_in; (void)out_size;
  const float* feature_u   = (const float*)d_in[0];
  const float* feature_v   = (const float*)d_in[1];
  const float* M_u         = (const float*)d_in[2];
  const float* M_v         = (const float*)d_in[3];
  const float* W           = (const float*)d_in[4];
  const float* Q           = (const float*)d_in[5];
  const float* side_u_f    = (const float*)d_in[6];
  const float* side_v_f    = (const float*)d_in[7];
  const float* w_side_u    = (const float*)d_in[8];
  const float* g_side_u    = (const float*)d_in[10];
  const float* beta_side_u = (const float*)d_in[11];
  const float* w_side_v    = (const float*)d_in[12];
  const float* g_side_v    = (const float*)d_in[14];
  const float* beta_side_v = (const float*)d_in[15];
  const float* w_cat_u     = (const float*)d_in[16];
  const float* g_cat_u     = (const float*)d_in[18];
  const float* beta_cat_u  = (const float*)d_in[19];
  const float* w_cat_v     = (const float*)d_in[20];
  const float* g_cat_v     = (const float*)d_in[22];
  const float* beta_cat_v  = (const float*)d_in[23];
  float* out = (float*)d_out;

  float* ws = (float*)d_ws;
  long off = 0;
  float* hv_pre   = ws + off; off += (long)R_DIM * V_DIM * H_DIM;  // hu_pre follows contiguously
  float* hu_pre   = ws + off; off += (long)R_DIM * U_DIM * H_DIM;
  float* hidden_u = ws + off; off += (long)R_DIM * U_DIM * H_DIM;  // hidden_v follows
  float* hidden_v = ws + off; off += (long)R_DIM * V_DIM * H_DIM;
  float* sideU    = ws + off; off += (long)U_DIM * SH_DIM;
  float* sideV    = ws + off; off += (long)V_DIM * SH_DIM;
  float* catU     = ws + off; off += (long)U_DIM * CAT_DIM;
  float* catV     = ws + off; off += (long)V_DIM * CAT_DIM;
  float* preU     = ws + off; off += (long)U_DIM * O_DIM;
  float* preV     = ws + off; off += (long)V_DIM * O_DIM;
  float* evT      = ws + off; off += (long)O_DIM * V_DIM;
  float* AQ       = ws + off; off += (long)R_DIM * U_DIM * O_DIM;
  float* mvSideU  = ws + off; off += 2 * SH_DIM;
  float* mvSideV  = ws + off; off += 2 * SH_DIM;
  float* mvCatU   = ws + off; off += 2 * O_DIM + 2;
  float* mvCatV   = ws + off; off += 2 * O_DIM + 2;
  float* P        = ws + off;  // K-split partials

  const long SLOT = 10L * 2000 * 64;
  const long avail = (long)(ws_size / sizeof(float));
  int KS = 4;
  if (off + 4L * SLOT > avail) KS = 2;
  if (off + (long)KS * SLOT > avail) KS = 1;

  dim3 blk(256);
  const long MN = 2000L * 64;

  // Stage A (split-bf16 MFMA): P[ks][z] = feature_{v|u} @ W[r]
  {
    G2 g{};
    g.A0 = feature_v; g.B0 = W; g.C0 = P;
    g.sA0 = 0; g.sB0 = (long)F_DIM * H_DIM; g.sC0 = MN;
    g.A1 = feature_u; g.B1 = W; g.C1 = P + 5 * MN;
    g.sA1 = 0; g.sB1 = (long)F_DIM * H_DIM; g.sC1 = MN;
    g.zSplit = R_DIM; g.M = 2000; g.N = H_DIM; g.K = F_DIM;
    mfma_gemm<true><<<dim3(32, KS, 10), blk, 0, stream>>>(g);
  }
  reduceKS<<<1250, blk, 0, stream>>>(P, hv_pre, SLOT / 4, SLOT / 4, KS, 0);

  // Side: side = side_feature @ w_side (bias cancels in BN)
  {
    G2 g{};
    g.A0 = side_u_f; g.B0 = w_side_u; g.C0 = sideU;
    g.sA0 = 0; g.sB0 = 0; g.sC0 = 0;
    g.A1 = side_v_f; g.B1 = w_side_v; g.C1 = sideV;
    g.sA1 = 0; g.sB1 = 0; g.sC1 = 0;
    g.zSplit = 1; g.M = U_DIM; g.N = SH_DIM; g.K = SF_DIM;
    gemm64<<<dim3(32, 1, 2), blk, 0, stream>>>(g);
  }

  // Stage B (split-bf16 MFMA): P[ks][z] = M_{u|v}[r] @ {hv|hu}_pre[r]
  {
    G2 g{};
    g.A0 = M_u; g.B0 = hv_pre; g.C0 = P;
    g.sA0 = (long)U_DIM * V_DIM; g.sB0 = MN; g.sC0 = MN;
    g.A1 = M_v; g.B1 = hu_pre; g.C1 = P + 5 * MN;
    g.sA1 = (long)V_DIM * U_DIM; g.sB1 = MN; g.sC1 = MN;
    g.zSplit = R_DIM; g.M = 2000; g.N = H_DIM; g.K = 2000;
    mfma_gemm<true><<<dim3(32, KS, 10), blk, 0, stream>>>(g);
  }
  reduceKS<<<1250, blk, 0, stream>>>(P, hidden_u, SLOT / 4, SLOT / 4, KS, 1);

  // Side BN + ReLU
  colstats2<<<dim3(SH_DIM, 2), blk, 0, stream>>>(sideU, sideV, U_DIM, SH_DIM,
                                                 mvSideU, mvSideV, 1e-5f);
  bn_apply2<<<dim3(500, 2), blk, 0, stream>>>(sideU, sideV, mvSideU, mvSideV,
                                              g_side_u, beta_side_u, g_side_v, beta_side_v,
                                              U_DIM, SH_DIM, nullptr);
  // cat = [hidden | pre | side]
  concat2<<<dim3(5500, 2), blk, 0, stream>>>(hidden_u, hu_pre, sideU,
                                             hidden_v, hv_pre, sideV, catU, catV, U_DIM);
  // cat GEMM: pre = cat @ w_cat
  {
    G2 g{};
    g.A0 = catU; g.B0 = w_cat_u; g.C0 = preU;
    g.sA0 = 0; g.sB0 = 0; g.sC0 = 0;
    g.A1 = catV; g.B1 = w_cat_v; g.C1 = preV;
    g.sA1 = 0; g.sB1 = 0; g.sC1 = 0;
    g.zSplit = 1; g.M = U_DIM; g.N = O_DIM; g.K = CAT_DIM;
    gemm64<<<dim3(32, 2, 2), blk, 0, stream>>>(g);
  }
  // cat BN + ReLU -> embed; v-half also writes evT = embed_v^T
  colstats2<<<dim3(O_DIM, 2), blk, 0, stream>>>(preU, preV, U_DIM, O_DIM,
                                                mvCatU, mvCatV, 1e-5f);
  bn_apply2<<<dim3(586, 2), blk, 0, stream>>>(preU, preV, mvCatU, mvCatV,
                                              g_cat_u, beta_cat_u, g_cat_v, beta_cat_v,
                                              U_DIM, O_DIM, evT);
  // E1: AQ[r] = embed_u @ Q[r]  (small, fp32)
  {
    G2 g{};
    g.A0 = preU; g.B0 = Q; g.C0 = AQ;
    g.sA0 = 0; g.sB0 = (long)O_DIM * O_DIM; g.sC0 = (long)U_DIM * O_DIM;
    g.A1 = preU; g.B1 = Q; g.C1 = AQ;
    g.sA1 = 0; g.sB1 = (long)O_DIM * O_DIM; g.sC1 = (long)U_DIM * O_DIM;
    g.zSplit = R_DIM; g.M = U_DIM; g.N = O_DIM; g.K = O_DIM;
    gemm64<<<dim3(32, 2, R_DIM), blk, 0, stream>>>(g);
  }
  // E2 (split-bf16 MFMA): score[r] = AQ[r] @ embed_v^T (via evT, NN, coalesced)
  {
    G2 g{};
    g.A0 = AQ; g.B0 = evT; g.C0 = out;
    g.sA0 = (long)U_DIM * O_DIM; g.sB0 = 0; g.sC0 = (long)U_DIM * V_DIM;
    g.A1 = AQ; g.B1 = evT; g.C1 = out;
    g.sA1 = (long)U_DIM * O_DIM; g.sB1 = 0; g.sC1 = (long)U_DIM * V_DIM;
    g.zSplit = R_DIM; g.M = U_DIM; g.N = V_DIM; g.K = O_DIM;
    mfma_gemm<false><<<dim3(32, 32, R_DIM), blk, 0, stream>>>(g);
  }
}